// Round 4
// baseline (718.006 us; speedup 1.0000x reference)
//
#include <hip/hip_runtime.h>

#define NBINS 10
#define MAIN_BLOCKS 2048
// ws layout: per-block partial slots, 32 floats apart:
//   part[b*32 + 0..9]  = cnt,  part[b*32 + 10..19] = conf_sum, part[b*32 + 20..29] = acc_sum
// Slots are WRITTEN (not accumulated) by each block -> no pre-zeroing kernel needed.

// --- kernel 1: per-row conf/pred + per-block binned partial sums ---
// Two rows per wave: lanes 0-31 handle row 2p, lanes 32-63 handle row 2p+1.
// Lane loads a float4 (16 B) -> one 1 KiB coalesced load per wave per row-pair.
__global__ __launch_bounds__(256) void ece_main(const float* __restrict__ logits,
                                                const int* __restrict__ targets,
                                                float* __restrict__ part, int n) {
    __shared__ float s_cnt[NBINS], s_conf[NBINS], s_acc[NBINS];
    __shared__ int s_t64;
    if (threadIdx.x < NBINS) {
        s_cnt[threadIdx.x] = 0.0f;
        s_conf[threadIdx.x] = 0.0f;
        s_acc[threadIdx.x] = 0.0f;
    }
    // targets dtype sniff (parallel, wave 0): int64 little-endian targets with
    // values in [0,128) have every odd int32 word == 0. P(false positive for
    // genuine int32 targets) ~ 128^-64.
    if ((threadIdx.x >> 6) == 0) {
        int odd = targets[2 * threadIdx.x + 1];
        unsigned long long nz = __ballot(odd != 0);
        if (threadIdx.x == 0) s_t64 = (nz == 0ULL) ? 1 : 0;
    }
    __syncthreads();
    const bool t64 = (s_t64 != 0);

    const int lane = threadIdx.x & 63;
    const int half = lane >> 5;    // which row of the pair this lane serves
    const int hl   = lane & 31;    // lane within the 32-lane half
    const int wave_in_block   = threadIdx.x >> 6;
    const int waves_per_block = blockDim.x >> 6;
    const long long wave_global =
        (long long)blockIdx.x * waves_per_block + wave_in_block;
    const long long nwaves = (long long)gridDim.x * waves_per_block;
    const long long npairs = ((long long)n + 1) >> 1;

    // upper bin edges (searchsorted-left: bin = #edges strictly < conf, clip 9)
    const float ue[9] = {0.1f, 0.2f, 0.3f, 0.4f, 0.5f, 0.6f, 0.7f, 0.8f, 0.9f};

    for (long long pair = wave_global; pair < npairs; pair += nwaves) {
        const long long row = pair * 2 + half;
        if (row >= n) continue;  // uniform within each 32-lane half -> shfl-safe

        const float4 v =
            *reinterpret_cast<const float4*>(logits + pair * 256 + lane * 4);

        // lane-local max of 4 + index (strict > keeps lowest index on ties)
        float m = v.x;
        int idx = hl * 4;
        if (v.y > m) { m = v.y; idx = hl * 4 + 1; }
        if (v.z > m) { m = v.z; idx = hl * 4 + 2; }
        if (v.w > m) { m = v.w; idx = hl * 4 + 3; }

        // half-wave max+argmax reduce (xor offsets < 32 stay within the half)
        #pragma unroll
        for (int off = 16; off >= 1; off >>= 1) {
            float om = __shfl_xor(m, off, 64);
            int   oi = __shfl_xor(idx, off, 64);
            if (om > m || (om == m && oi < idx)) { m = om; idx = oi; }
        }

        // sum of exp(l - max); the max element contributes exp(0)=1 exactly,
        // so conf = 1/s matches max(softmax) structurally
        float s = __expf(v.x - m) + __expf(v.y - m) +
                  __expf(v.z - m) + __expf(v.w - m);
        #pragma unroll
        for (int off = 16; off >= 1; off >>= 1)
            s += __shfl_xor(s, off, 64);

        if (hl == 0) {
            float conf = 1.0f / s;
            int bin = 0;
            #pragma unroll
            for (int k = 0; k < 9; ++k) bin += (conf > ue[k]) ? 1 : 0;
            const int tgt = t64 ? targets[2 * row] : targets[row];
            float acc = (idx == tgt) ? 1.0f : 0.0f;
            atomicAdd(&s_cnt[bin], 1.0f);
            atomicAdd(&s_conf[bin], conf);
            atomicAdd(&s_acc[bin], acc);
        }
    }
    __syncthreads();

    if (threadIdx.x < NBINS) {
        float* slot = part + (size_t)blockIdx.x * 32;
        slot[threadIdx.x]             = s_cnt[threadIdx.x];
        slot[NBINS + threadIdx.x]     = s_conf[threadIdx.x];
        slot[2 * NBINS + threadIdx.x] = s_acc[threadIdx.x];
    }
}

// --- kernel 2: reduce per-block partials + scalar epilogue ---
__global__ __launch_bounds__(256) void ece_final(const float* __restrict__ part,
                                                 float* __restrict__ out,
                                                 int n, int nblocks) {
    __shared__ float tot[3 * NBINS];
    if (threadIdx.x < 3 * NBINS) tot[threadIdx.x] = 0.0f;
    __syncthreads();

    float loc[3 * NBINS];
    #pragma unroll
    for (int k = 0; k < 3 * NBINS; ++k) loc[k] = 0.0f;

    for (int b = threadIdx.x; b < nblocks; b += blockDim.x) {
        const float* slot = part + (size_t)b * 32;
        #pragma unroll
        for (int k = 0; k < 3 * NBINS; ++k) loc[k] += slot[k];
    }
    #pragma unroll
    for (int k = 0; k < 3 * NBINS; ++k) atomicAdd(&tot[k], loc[k]);
    __syncthreads();

    if (threadIdx.x == 0) {
        float ece = 0.0f;
        for (int b = 0; b < NBINS; ++b) {
            float cnt = tot[b];
            if (cnt > 0.0f) {
                float avg_conf = tot[NBINS + b] / cnt;
                float avg_acc  = tot[2 * NBINS + b] / cnt;
                float frac = cnt / (float)n;
                ece += fabsf(avg_conf - avg_acc) * frac;
            }
        }
        out[0] = ece;
    }
}

extern "C" void kernel_launch(void* const* d_in, const int* in_sizes, int n_in,
                              void* d_out, int out_size, void* d_ws, size_t ws_size,
                              hipStream_t stream) {
    const float* logits = (const float*)d_in[0];
    const int* targets = (const int*)d_in[1];
    float* part = (float*)d_ws;       // 2048 * 32 floats = 256 KB
    float* out = (float*)d_out;
    const int n = in_sizes[0] >> 7;   // rows = logits elements / 128 (dtype-proof)

    hipLaunchKernelGGL(ece_main, dim3(MAIN_BLOCKS), dim3(256), 0, stream,
                       logits, targets, part, n);
    hipLaunchKernelGGL(ece_final, dim3(1), dim3(256), 0, stream,
                       part, out, n, MAIN_BLOCKS);
}